// Round 3
// baseline (109.662 us; speedup 1.0000x reference)
//
#include <hip/hip_runtime.h>

#define NB 4096
#define NC 8192

// One wave (64 lanes) per (row, matrix). Streams the row computing:
//  - conf-weighted BCE row sum: arg = |p + t - 1| (t in {0,1}),
//    grouped as log2(a0*a1*a2*a3)*ln2 -> one v_log_f32 per float4.
//  - wave-SHARED top-6 (by score): one ballot per float4 on the lane's
//    4-element max vs the exact running 6th-max threshold; rare slow path
//    does serial readlane inserts under wave-uniform branches.
__global__ __launch_bounds__(256) void row_stats(
    const float* __restrict__ tk_s, const float* __restrict__ g_s,
    const float* __restrict__ tk_t, const float* __restrict__ g_t,
    const float* __restrict__ conf, float* __restrict__ ws) {
  const int lane = threadIdx.x & 63;
  const int wave = threadIdx.x >> 6;
  const int row  = (blockIdx.x << 2) + wave;
  const int mat  = blockIdx.y;

  const float4* S4 = reinterpret_cast<const float4*>(
      (mat ? g_s : tk_s) + (size_t)row * NC);
  const float4* T4 = reinterpret_cast<const float4*>(
      (mat ? g_t : tk_t) + (size_t)row * NC);

  // wave-uniform shared top-6 (desc). keys = f32 bits (scores>0 -> monotonic).
  unsigned lk0=0,lk1=0,lk2=0,lk3=0,lk4=0,lk5=0;
  unsigned lp0=0,lp1=0,lp2=0,lp3=0,lp4=0,lp5=0;
  float bl2 = 0.0f;             // sum of log2(arg); bce_row_sum = -bl2*ln2
  unsigned tseed;               // (lower bound on row 6th-max bits) - 1

  // ---- 2-deep prefetch + seed threshold from iter 0 ----
  float4 s0 = S4[lane],      t0 = T4[lane];
  float4 s1 = S4[64 + lane], t1 = T4[64 + lane];
  {
    float m4 = fmaxf(fmaxf(s0.x, s0.y), fmaxf(s0.z, s0.w));
    // group-of-8-lanes max (8 disjoint groups -> 8 distinct elements)
    m4 = fmaxf(m4, __shfl_xor(m4, 1));
    m4 = fmaxf(m4, __shfl_xor(m4, 2));
    m4 = fmaxf(m4, __shfl_xor(m4, 4));
    // min over the 8 group-maxes: >=8 elements >= m -> m <= row 6th-max
    m4 = fminf(m4, __shfl_xor(m4, 8));
    m4 = fminf(m4, __shfl_xor(m4, 16));
    m4 = fminf(m4, __shfl_xor(m4, 32));
    tseed = __float_as_uint(m4) - 1u;  // admit equality under strict >
  }

#define INS(KJ, PJ) { if (ck_ > KJ) { unsigned tk_ = KJ, tp_ = PJ;        \
    KJ = ck_; PJ = cp_; ck_ = tk_; cp_ = tp_; } }
#define TRY(KE, QE, CE) { unsigned key_ = __builtin_amdgcn_readlane(KE, l_); \
    if (key_ > lk5) {                                                     \
      unsigned ck_ = key_;                                                \
      unsigned cp_ = ((unsigned)(CE) << 1) |                              \
                     (unsigned)((QE >> l_) & 1ull);                       \
      INS(lk0, lp0) INS(lk1, lp1) INS(lk2, lp2)                           \
      INS(lk3, lp3) INS(lk4, lp4) INS(lk5, lp5)                           \
    } }

  auto process = [&](float4 sv, float4 tv, int i) {
    // BCE: arg_e = |s_e + t_e - 1|; abs folds into product input modifiers
    float b0 = (sv.x + tv.x) - 1.0f;
    float b1 = (sv.y + tv.y) - 1.0f;
    float b2 = (sv.z + tv.z) - 1.0f;
    float b3 = (sv.w + tv.w) - 1.0f;
    float pr = (fabsf(b0) * fabsf(b1)) * (fabsf(b2) * fabsf(b3));
    bl2 += __log2f(pr);
    // top-k filter: one ballot per lane-quad
    float m4 = fmaxf(fmaxf(sv.x, sv.y), fmaxf(sv.z, sv.w));
    float thrf = __uint_as_float(lk5 > tseed ? lk5 : tseed);
    unsigned long long m_ = __ballot(m4 > thrf);
    if (m_) {
      unsigned long long q0 = __ballot(tv.x > 0.5f);
      unsigned long long q1 = __ballot(tv.y > 0.5f);
      unsigned long long q2 = __ballot(tv.z > 0.5f);
      unsigned long long q3 = __ballot(tv.w > 0.5f);
      unsigned kx = __float_as_uint(sv.x), ky = __float_as_uint(sv.y);
      unsigned kz = __float_as_uint(sv.z), kw = __float_as_uint(sv.w);
      do {
        int l_ = __ffsll(m_) - 1;
        m_ &= m_ - 1;
        unsigned c_ = (unsigned)(((i) * 64 + l_) * 4);
        TRY(kx, q0, c_)
        TRY(ky, q1, c_ + 1)
        TRY(kz, q2, c_ + 2)
        TRY(kw, q3, c_ + 3)
      } while (m_);
    }
  };

  // ---- main loop, loads pipelined two iterations ahead ----
  #pragma unroll 2
  for (int i = 0; i < 30; ++i) {
    float4 sn = S4[(i + 2) * 64 + lane];
    float4 tn = T4[(i + 2) * 64 + lane];
    process(s0, t0, i);
    s0 = s1; t0 = t1; s1 = sn; t1 = tn;
  }
  process(s0, t0, 30);
  process(s1, t1, 31);
#undef TRY
#undef INS

  // wave-reduce log2 sum (butterfly)
  #pragma unroll
  for (int off = 32; off > 0; off >>= 1) bl2 += __shfl_xor(bl2, off);

  if (lane == 0) {
    // first <=2 negatives (target bit 0) in descending score order
    float nsum = 0.0f; int cnt = 0;
#define SELN(ki, pi) { if (((pi) & 1u) == 0u && cnt < 2) {                \
      nsum += -__logf(1.0f - __uint_as_float(ki)); cnt++; } }
    SELN(lk0, lp0) SELN(lk1, lp1) SELN(lk2, lp2)
    SELN(lk3, lp3) SELN(lk4, lp4) SELN(lk5, lp5)
#undef SELN
    const int base = mat * NB + row;
    const float ln2 = 0.6931471805599453f;
    ws[base]          = conf[row] * (-bl2 * ln2);  // conf-weighted bce row sum
    ws[2 * NB + base] = nsum;                      // hard-negative bce sum
    ws[4 * NB + base] = (float)cnt;                // hard-negative count
  }
}

// Deterministic single-block reduction + final loss math.
__global__ __launch_bounds__(256) void finalize_loss(
    const float* __restrict__ ws, float* __restrict__ out) {
  __shared__ float red[6][256];
  const int t = threadIdx.x;
  float a[6] = {0.f, 0.f, 0.f, 0.f, 0.f, 0.f};
  for (int r = t; r < NB; r += 256) {
    #pragma unroll
    for (int j = 0; j < 6; ++j) a[j] += ws[j * NB + r];
  }
  #pragma unroll
  for (int j = 0; j < 6; ++j) red[j][t] = a[j];
  __syncthreads();
  for (int s = 128; s > 0; s >>= 1) {
    if (t < s) {
      #pragma unroll
      for (int j = 0; j < 6; ++j) red[j][t] += red[j][t + s];
    }
    __syncthreads();
  }
  if (t == 0) {
    const float inv = 1.0f / ((float)NB * (float)NC);
    float tk = red[0][0] * inv + 0.5f * (red[2][0] / (red[4][0] + 1e-8f));
    float g  = red[1][0] * inv + 0.5f * (red[3][0] / (red[5][0] + 1e-8f));
    out[0] = 0.6f * tk + 0.4f * g;
    out[1] = tk;
    out[2] = g;
  }
}

extern "C" void kernel_launch(void* const* d_in, const int* in_sizes, int n_in,
                              void* d_out, int out_size, void* d_ws, size_t ws_size,
                              hipStream_t stream) {
  const float* tk_s = (const float*)d_in[0];
  const float* g_s  = (const float*)d_in[1];
  const float* tk_t = (const float*)d_in[2];
  const float* g_t  = (const float*)d_in[3];
  const float* conf = (const float*)d_in[4];
  float* ws  = (float*)d_ws;   // 6*NB floats = 96 KB
  float* out = (float*)d_out;  // 3 floats: total, tk_loss, g_loss

  dim3 grid(NB / 4, 2);        // 4 rows per block (one per wave), 2 matrices
  row_stats<<<grid, 256, 0, stream>>>(tk_s, g_s, tk_t, g_t, conf, ws);
  finalize_loss<<<1, 256, 0, stream>>>(ws, out);
}